// Round 2
// baseline (158.339 us; speedup 1.0000x reference)
//
#include <hip/hip_runtime.h>

// Problem constants (from reference): BZ=64, P=512, T=256, H=768
#define BZ 64
#define P  512
#define T  256
#define H  768
#define H4 (H / 4)            // 192 float4 per row
#define CHUNKS 16             // blocks per batch
#define TOK_PER_CHUNK (T / CHUNKS)          // 16 tokens
#define F4_PER_CHUNK (TOK_PER_CHUNK * H4)   // 3072 float4
#define ITERS (F4_PER_CHUNK / 256)          // 12 per thread

// Fused kernel: each block recomputes the per-batch subword-offset scan in LDS
// (cheap: 1 KB load + 8 Hillis-Steele rounds), then streams its 16-token slice
// of the output. Token t averages rows [start, start+len) of enc_out[b];
// len==0 -> zeros. One dispatch, no workspace.
__global__ __launch_bounds__(256)
void fused_bert_merge(const float* __restrict__ enc,
                      const int* __restrict__ lens,
                      float* __restrict__ out) {
    __shared__ int s_incl[T];   // inclusive prefix sums
    __shared__ int s_len[T];

    const int b     = blockIdx.x >> 4;          // / CHUNKS
    const int chunk = blockIdx.x & (CHUNKS - 1);
    const int tid   = threadIdx.x;

    const int v = lens[b * T + tid];
    s_len[tid]  = v;
    s_incl[tid] = v;
    __syncthreads();
    #pragma unroll
    for (int off = 1; off < T; off <<= 1) {
        const int add = (tid >= off) ? s_incl[tid - off] : 0;
        __syncthreads();
        s_incl[tid] += add;
        __syncthreads();
    }

    const int t0 = chunk * TOK_PER_CHUNK;
    const float4* encb = (const float4*)(enc + (size_t)b * P * H);
    float4* outb       = (float4*)(out + ((size_t)b * T + t0) * H);

    #pragma unroll
    for (int it = 0; it < ITERS; ++it) {
        const int i    = it * 256 + tid;        // [0, 3072) within chunk
        const int trel = i / H4;                // token within chunk
        const int h4   = i - trel * H4;
        const int tok  = t0 + trel;

        const int len   = s_len[tok];
        const int start = s_incl[tok] - len;    // exclusive prefix

        float4 r = make_float4(0.f, 0.f, 0.f, 0.f);
        if (len > 0) {
            const float4* row = encb + (size_t)start * H4 + h4;
            r = row[0];
            if (len > 1) {
                #pragma unroll 1
                for (int k = 1; k < len; ++k) {
                    const float4 r2 = row[(size_t)k * H4];
                    r.x += r2.x; r.y += r2.y; r.z += r2.z; r.w += r2.w;
                }
                const float inv = 1.0f / (float)len;
                r.x *= inv; r.y *= inv; r.z *= inv; r.w *= inv;
            }
        }
        outb[i] = r;
    }
}

extern "C" void kernel_launch(void* const* d_in, const int* in_sizes, int n_in,
                              void* d_out, int out_size, void* d_ws, size_t ws_size,
                              hipStream_t stream) {
    const float* enc  = (const float*)d_in[0];  // enc_out (BZ,P,H) f32
    // d_in[1] = bert_mask (unused; redundant with lens)
    const int*   lens = (const int*)d_in[2];    // bert_lens (BZ,T) i32
    float*       out  = (float*)d_out;          // (BZ,T,H) f32

    fused_bert_merge<<<BZ * CHUNKS, 256, 0, stream>>>(enc, lens, out);
}